// Round 2
// baseline (603.331 us; speedup 1.0000x reference)
//
#include <hip/hip_runtime.h>

#define NALGOS 64
#define NTASKS 1024
#define LXLEN  512
#define TOUT   (LXLEN + 1)   // 513
#define PDEPTH 16            // phase1 row-pipeline depth (was 8)
#define PROWS  (LXLEN + PDEPTH)

__device__ __forceinline__ float rdlane(float v, int lane) {
    return __int_as_float(__builtin_amdgcn_readlane(__float_as_int(v), lane));
}

// ---------------------------------------------------------------------------
// Phase 0: materialize P[t][i] = tm[lx[t]][lx[i]] (512x512, 1 MB) with full
// parallelism so phase1's per-step loads become lane-coalesced.
// ---------------------------------------------------------------------------
__global__ __launch_bounds__(256) void phase0_kernel(
    const int* __restrict__ lx, const float* __restrict__ tm,
    float* __restrict__ P)
{
    const int t = blockIdx.x;          // 0..PROWS-1
    const int i = threadIdx.x;
    if (t < LXLEN) {
        const int row = lx[t] * NTASKS;
        P[t * LXLEN + i]       = tm[row + lx[i]];
        P[t * LXLEN + i + 256] = tm[row + lx[i + 256]];
    } else {                            // pad rows: loaded by phase1, unused
        P[t * LXLEN + i]       = 0.f;
        P[t * LXLEN + i + 256] = 0.f;
    }
}

// ---------------------------------------------------------------------------
// Phase 1: per-algo scalar coefficient chain. One wave per algo, 64 blocks.
// NEW: 16-deep row pipeline (G[16][8], ~160 VGPR, 1 wave/block so free).
// Prefetch distance 16 steps (~740 cyc) now covers LLC/HBM-miss latency on
// the P refill; was 8 steps (~370 cyc), marginal for L2 and too short for
// LLC. g-loop unrolled in PAIRS so the G row index jb+j stays compile-time
// (runtime index would spill G to scratch, rule #20).
// ---------------------------------------------------------------------------
__global__ __launch_bounds__(64) void phase1_kernel(
    const int*   __restrict__ lx,
    const float* __restrict__ P,
    const float* __restrict__ diff,
    const float* __restrict__ eff_g,
    const float* __restrict__ mem_g,
    const float* __restrict__ boost_g,
    float*       __restrict__ coef_out)
{
    const int a = blockIdx.x, lane = threadIdx.x;

    float nk[8]; float V[8];
    #pragma unroll
    for (int k = 0; k < 8; ++k) {
        const int tsk = lx[lane + 64 * k];
        nk[k] = -1.4426950408889634f / diff[tsk];
        V[k] = 0.f;
    }
    const float eff = eff_g[a], mem = mem_g[a], boost = boost_g[a];

    // prime 16-deep row pipeline: G[d][k] = P[d][64k+lane], d = 0..15
    float G[PDEPTH][8];
    #pragma unroll
    for (int d = 0; d < PDEPTH; ++d)
        #pragma unroll
        for (int k = 0; k < 8; ++k)
            G[d][k] = P[d * LXLEN + 64 * k + lane];

    float coef = eff;
    float* cout = coef_out + (size_t)a * LXLEN;

    #pragma unroll
    for (int q = 0; q < 8; ++q) {
        float cbuf = 0.f;
        for (int gg = 0; gg < 4; ++gg) {          // runtime loop, pair-unrolled
            #pragma unroll
            for (int h = 0; h < 2; ++h) {         // g = 2*gg + h
                const int g  = 2 * gg + h;
                const int jb = h << 3;            // (g&1)*8, compile-time
                const int tb = q * 64 + g * 8;
                #pragma unroll
                for (int j = 0; j < 8; ++j) {
                    // ---- serial chain ----
                    const float p = V[q] * nk[q];
                    float x = rdlane(p, g * 8 + j);    // uniform lane select
                    x = fminf(fmaxf(x, -126.f), 126.f);
                    const float e = __builtin_exp2f(x);
                    const float u = (1.f - e) * __builtin_amdgcn_rcpf(1.f + e);
                    coef = __builtin_fmaf(u, boost, eff);
                    cbuf = (lane == g * 8 + j) ? coef : cbuf;
                    // ---- V update, future regs only ----
                    #pragma unroll
                    for (int k = q; k < 8; ++k)
                        V[k] = __builtin_fmaf(V[k], mem, G[jb + j][k] * coef);
                    // ---- refill row t+16, lane-coalesced ----
                    const float* rp = P + (tb + j + PDEPTH) * LXLEN + lane;
                    #pragma unroll
                    for (int k = q; k < 8; ++k)
                        G[jb + j][k] = rp[64 * k];
                }
            }
        }
        cout[q * 64 + lane] = cbuf;               // coalesced, 1/chunk
    }
}

// ---------------------------------------------------------------------------
// Phase 2: barrier-free bulk pass. NEW this round: 8 t-chunks of 64 (grid
// 2048 = 8 blocks/CU target, was 4) to fix the latency-bound profile
// (VALUBusy 18%, occ 30%, write stream at 2 TB/s vs 6.3 achievable). To fit
// 7-8 blocks/CU the per-thread ring shrinks to a SINGLE-buffered 16-slot
// interleaved ring ring[16][257] (16.4 KB; column-per-thread -> flush reads
// and scalar writes are bank-conflict-free). Per round kk (values v =
// 16kk+j, slot(v) = (v+phi)&15, phi=(n+1)&15, hp=16-phi):
//   1. write sb[j<hp]  -> slots [phi,16)   (new head of granule kk-1)
//   2. read slots [0,16) = granule kk-1, store as 4x dwordx4 (64B-aligned)
//   3. write sb[j>=hp] -> slots [0,phi)    (overwrites consumed values)
// Round 0 stores the head partial direct from regs; tail partial read back
// after the loop. Chunk c=1 is now EXACT (warm=64 = full history); c>=2
// keep warm=128 (mem^128 ~1e-12, unchanged approximation). launch_bounds
// (256,7) caps VGPR at 73 (est. peak ~66: rbuf16+nbuf16+sb16+quad temps).
// ---------------------------------------------------------------------------
__global__ __launch_bounds__(256, 7) void phase2_kernel(
    const int*   __restrict__ lx,
    const float* __restrict__ tm,
    const float* __restrict__ diff,
    const float* __restrict__ mem_g,
    const float* __restrict__ coef,
    float*       __restrict__ out)
{
    const int b = blockIdx.x;              // 2048 blocks: a*32 + c*4 + seg
    const int a = b >> 5;
    const int c = (b >> 2) & 7;
    const int n = ((b & 3) << 8) | threadIdx.x;
    const int warm = (c >= 2) ? 128 : 64 * c;   // c=0,1 exact; c>=2 approx
    const int t0   = 64 * c - warm;
    const int len  = warm + 64;

    __shared__ __align__(16) int   task_sh[216];
    __shared__ __align__(16) float coef_sh[216];
    __shared__ __align__(16) float ring[16 * 257];   // 16.4 KB, [slot][tid]

    for (int i = threadIdx.x; i < len + 16; i += 256) {
        const int t = t0 + i;
        task_sh[i] = (t < LXLEN) ? lx[t] : 0;
        coef_sh[i] = (t < LXLEN) ? coef[a * LXLEN + t] : 0.f;
    }

    const float mem   = mem_g[a];
    const float negkd = -1.4426950408889634f / diff[n];
    float* outp = out + ((size_t)a * NTASKS + n) * TOUT;
    float r = 0.f;
    float* ringc = ring + threadIdx.x;     // this thread's column

    // absolute float index of output v is ≡ n + 1 + v (mod 16)  (513≡1,
    // 64c≡0, 1024≡0 mod 16) -> granule phase is chunk-independent.
    const int phi = (n + 1) & 15;
    const int hp  = 16 - phi;              // head length, 1..16

    __syncthreads();

    float rbuf[16];
    #pragma unroll
    for (int j = 0; j < 16; ++j) {
        const int tk = __builtin_amdgcn_readfirstlane(task_sh[j]);
        rbuf[j] = tm[(size_t)tk * NTASKS + n];
    }

    // warmup: r-recurrence only, rolling 16-row pipeline
    for (int base = 0; base < warm; base += 16) {
        float nbuf[16];
        #pragma unroll
        for (int j = 0; j < 16; ++j) {
            const int tk = __builtin_amdgcn_readfirstlane(task_sh[base + 16 + j]);
            nbuf[j] = tm[(size_t)tk * NTASKS + n];
        }
        #pragma unroll
        for (int v = 0; v < 4; ++v) {
            const float4 cq = *(const float4*)&coef_sh[base + 4 * v];
            r = __builtin_fmaf(r, mem, rbuf[4 * v + 0] * cq.x);
            r = __builtin_fmaf(r, mem, rbuf[4 * v + 1] * cq.y);
            r = __builtin_fmaf(r, mem, rbuf[4 * v + 2] * cq.z);
            r = __builtin_fmaf(r, mem, rbuf[4 * v + 3] * cq.w);
        }
        #pragma unroll
        for (int j = 0; j < 16; ++j) rbuf[j] = nbuf[j];
    }

    if (c == 0) outp[0] = 0.f;
    float* op = outp + 64 * c + 1;

    #pragma unroll
    for (int kk = 0; kk < 4; ++kk) {       // 4 output rounds of 16
        const int base = warm + 16 * kk;
        float nbuf[16];
        #pragma unroll
        for (int j = 0; j < 16; ++j) {
            const int tk = __builtin_amdgcn_readfirstlane(task_sh[base + 16 + j]);
            nbuf[j] = tm[(size_t)tk * NTASKS + n];
        }
        float sb[16];
        #pragma unroll
        for (int v = 0; v < 4; ++v) {
            const float4 cq = *(const float4*)&coef_sh[base + 4 * v];
            const float cf[4] = { cq.x, cq.y, cq.z, cq.w };
            #pragma unroll
            for (int u = 0; u < 4; ++u) {
                const int j = 4 * v + u;
                r = __builtin_fmaf(r, mem, rbuf[j] * cf[u]);
                float x = r * negkd;
                x = fminf(fmaxf(x, -126.f), 126.f);
                const float e = __builtin_exp2f(x);
                sb[j] = (1.f - e) * __builtin_amdgcn_rcpf(1.f + e);
            }
        }

        if (kk == 0) {
            // head partial: v in [0,hp) straight from regs (predicated)
            #pragma unroll
            for (int j = 0; j < 16; ++j)
                if (j < hp) op[j] = sb[j];
            // stash v in [hp,16) -> slots [0,phi)
            #pragma unroll
            for (int j = 0; j < 16; ++j)
                if (j >= hp) ringc[(j - hp) * 257] = sb[j];
        } else {
            // 1. new head of granule kk-1 -> slots [phi,16)
            #pragma unroll
            for (int j = 0; j < 16; ++j)
                if (j < hp) ringc[(j + phi) * 257] = sb[j];
            // 2. flush granule kk-1 (slot i holds its i-th value), aligned
            float* dst = op + hp + 16 * (kk - 1);
            #pragma unroll
            for (int qd = 0; qd < 4; ++qd) {
                float4 w;
                w.x = ringc[(4 * qd + 0) * 257];
                w.y = ringc[(4 * qd + 1) * 257];
                w.z = ringc[(4 * qd + 2) * 257];
                w.w = ringc[(4 * qd + 3) * 257];
                ((float4*)dst)[qd] = w;
            }
            // 3. stash v in [16kk+hp,16kk+16) -> slots [0,phi)
            #pragma unroll
            for (int j = 0; j < 16; ++j)
                if (j >= hp) ringc[(j - hp) * 257] = sb[j];
        }
        #pragma unroll
        for (int j = 0; j < 16; ++j) rbuf[j] = nbuf[j];
    }

    // tail partial: v in [hp+48,64) sits in slots [0,phi) (predicated)
    #pragma unroll
    for (int j = 0; j < 16; ++j)
        if (j < phi) op[hp + 48 + j] = ringc[j * 257];
}

// ---------------------------------------------------------------------------
// Fallback (validated R1 kernel): used only if ws can't hold coef + P.
// ---------------------------------------------------------------------------
__global__ __launch_bounds__(1024) void fused_fallback_kernel(
    const int* __restrict__ lx, const float* __restrict__ tm,
    const float* __restrict__ diff, const float* __restrict__ eff_g,
    const float* __restrict__ mem_g, const float* __restrict__ boost_g,
    float* __restrict__ out)
{
    const int a = blockIdx.x, n = threadIdx.x;
    __shared__ int lx_sh[LXLEN];
    __shared__ float sbuf[2];
    if (n < LXLEN) lx_sh[n] = lx[n];
    if (n == 0) sbuf[0] = 0.0f;
    const float eff = eff_g[a], mem = mem_g[a], boost = boost_g[a];
    const float negkd = -1.4426950408889634f / diff[n];
    float* outp = out + ((size_t)a * NTASKS + n) * TOUT;
    outp[0] = 0.0f;
    float r = 0.0f;
    __syncthreads();
    for (int t = 0; t < LXLEN; ++t) {
        const int task = lx_sh[t];
        const float s = sbuf[t & 1];
        const float coef = __builtin_fmaf(s, boost, eff);
        const float row = tm[task * NTASKS + n];
        r = __builtin_fmaf(r, mem, row * coef);
        float x = r * negkd;
        x = fminf(fmaxf(x, -126.0f), 126.0f);
        const float e = __builtin_exp2f(x);
        const float sig = (1.0f - e) * __builtin_amdgcn_rcpf(1.0f + e);
        outp[t + 1] = sig;
        if (t + 1 < LXLEN && n == lx_sh[t + 1]) sbuf[(t + 1) & 1] = sig;
        __syncthreads();
    }
}

extern "C" void kernel_launch(void* const* d_in, const int* in_sizes, int n_in,
                              void* d_out, int out_size, void* d_ws, size_t ws_size,
                              hipStream_t stream) {
    const int*   lx    = (const int*)  d_in[0];
    const float* tm    = (const float*)d_in[1];
    const float* diff  = (const float*)d_in[2];
    const float* eff   = (const float*)d_in[3];
    const float* mem   = (const float*)d_in[4];
    const float* boost = (const float*)d_in[5];
    float* out = (float*)d_out;

    const size_t coef_elems = (size_t)NALGOS * LXLEN;
    const size_t P_elems    = (size_t)PROWS * LXLEN;
    const size_t need_bytes = (coef_elems + P_elems) * sizeof(float);

    if (ws_size >= need_bytes) {
        float* coef = (float*)d_ws;
        float* P    = coef + coef_elems;
        phase0_kernel<<<dim3(PROWS), dim3(256), 0, stream>>>(lx, tm, P);
        phase1_kernel<<<dim3(NALGOS), dim3(64), 0, stream>>>(
            lx, P, diff, eff, mem, boost, coef);
        phase2_kernel<<<dim3(NALGOS * 32), dim3(256), 0, stream>>>(
            lx, tm, diff, mem, coef, out);
    } else {
        fused_fallback_kernel<<<dim3(NALGOS), dim3(NTASKS), 0, stream>>>(
            lx, tm, diff, eff, mem, boost, out);
    }
}

// Round 3
// 602.745 us; speedup vs baseline: 1.0010x; 1.0010x over previous
//
#include <hip/hip_runtime.h>

#define NALGOS 64
#define NTASKS 1024
#define LXLEN  512
#define TOUT   (LXLEN + 1)   // 513
#define PDEPTH 16            // phase1 row-pipeline depth
#define PROWS  (LXLEN + PDEPTH)

__device__ __forceinline__ float rdlane(float v, int lane) {
    return __int_as_float(__builtin_amdgcn_readlane(__float_as_int(v), lane));
}

// ---------------------------------------------------------------------------
// Phase 0: materialize P[t][i] = tm[lx[t]][lx[i]] (512x512, 1 MB) with full
// parallelism so phase1's per-step loads become lane-coalesced.
// ---------------------------------------------------------------------------
__global__ __launch_bounds__(256) void phase0_kernel(
    const int* __restrict__ lx, const float* __restrict__ tm,
    float* __restrict__ P)
{
    const int t = blockIdx.x;          // 0..PROWS-1
    const int i = threadIdx.x;
    if (t < LXLEN) {
        const int row = lx[t] * NTASKS;
        P[t * LXLEN + i]       = tm[row + lx[i]];
        P[t * LXLEN + i + 256] = tm[row + lx[i + 256]];
    } else {                            // pad rows: loaded by phase1, unused
        P[t * LXLEN + i]       = 0.f;
        P[t * LXLEN + i + 256] = 0.f;
    }
}

// ---------------------------------------------------------------------------
// Phase 1: per-algo scalar coefficient chain. One wave per algo, 64 blocks.
// 16-deep row pipeline G[16][8] = 128 VGPRs. ROUND-2 POST-MORTEM: with
// __launch_bounds__(64) alone the allocator capped at 92 VGPRs and spilled
// G to scratch (402 us, occ 0.75%). Fix: explicit min-waves=1 ->> budget up
// to 512 VGPRs, live set ~180, no spill. g-loop unrolled in PAIRS so the G
// row index jb+j stays compile-time (runtime index -> scratch, rule #20).
// ---------------------------------------------------------------------------
__global__ __launch_bounds__(64, 1) void phase1_kernel(
    const int*   __restrict__ lx,
    const float* __restrict__ P,
    const float* __restrict__ diff,
    const float* __restrict__ eff_g,
    const float* __restrict__ mem_g,
    const float* __restrict__ boost_g,
    float*       __restrict__ coef_out)
{
    const int a = blockIdx.x, lane = threadIdx.x;

    float nk[8]; float V[8];
    #pragma unroll
    for (int k = 0; k < 8; ++k) {
        const int tsk = lx[lane + 64 * k];
        nk[k] = -1.4426950408889634f / diff[tsk];
        V[k] = 0.f;
    }
    const float eff = eff_g[a], mem = mem_g[a], boost = boost_g[a];

    // prime 16-deep row pipeline: G[d][k] = P[d][64k+lane], d = 0..15
    float G[PDEPTH][8];
    #pragma unroll
    for (int d = 0; d < PDEPTH; ++d)
        #pragma unroll
        for (int k = 0; k < 8; ++k)
            G[d][k] = P[d * LXLEN + 64 * k + lane];

    float coef = eff;
    float* cout = coef_out + (size_t)a * LXLEN;

    #pragma unroll
    for (int q = 0; q < 8; ++q) {
        float cbuf = 0.f;
        for (int gg = 0; gg < 4; ++gg) {          // runtime loop, pair-unrolled
            #pragma unroll
            for (int h = 0; h < 2; ++h) {         // g = 2*gg + h
                const int g  = 2 * gg + h;
                const int jb = h << 3;            // (g&1)*8, compile-time
                const int tb = q * 64 + g * 8;
                #pragma unroll
                for (int j = 0; j < 8; ++j) {
                    // ---- serial chain ----
                    const float p = V[q] * nk[q];
                    float x = rdlane(p, g * 8 + j);    // uniform lane select
                    x = fminf(fmaxf(x, -126.f), 126.f);
                    const float e = __builtin_exp2f(x);
                    const float u = (1.f - e) * __builtin_amdgcn_rcpf(1.f + e);
                    coef = __builtin_fmaf(u, boost, eff);
                    cbuf = (lane == g * 8 + j) ? coef : cbuf;
                    // ---- V update, future regs only ----
                    #pragma unroll
                    for (int k = q; k < 8; ++k)
                        V[k] = __builtin_fmaf(V[k], mem, G[jb + j][k] * coef);
                    // ---- refill row t+16, lane-coalesced ----
                    const float* rp = P + (tb + j + PDEPTH) * LXLEN + lane;
                    #pragma unroll
                    for (int k = q; k < 8; ++k)
                        G[jb + j][k] = rp[64 * k];
                }
            }
        }
        cout[q * 64 + lane] = cbuf;               // coalesced, 1/chunk
    }
}

// ---------------------------------------------------------------------------
// Phase 2: barrier-free bulk pass. 8 t-chunks of 64 (grid 2048 = 8 blocks/CU
// target) for latency hiding. Single-buffered 16-slot interleaved ring
// ring[16][257] (16.4 KB; column-per-thread -> flush reads and scalar writes
// near-conflict-free). Per round kk (values v = 16kk+j, slot(v) = (v+phi)&15,
// phi=(n+1)&15, hp=16-phi):
//   1. write sb[j<hp]  -> slots [phi,16)   (new head of granule kk-1)
//   2. read slots [0,16) = granule kk-1, store as 4x dwordx4 (64B-aligned)
//   3. write sb[j>=hp] -> slots [0,phi)    (overwrites consumed values)
// Round 0 stores the head partial direct from regs; tail partial read back
// after the loop. Chunks c=0,1 exact; c>=2 warm=128 (mem^128 ~1e-12).
// ---------------------------------------------------------------------------
__global__ __launch_bounds__(256, 7) void phase2_kernel(
    const int*   __restrict__ lx,
    const float* __restrict__ tm,
    const float* __restrict__ diff,
    const float* __restrict__ mem_g,
    const float* __restrict__ coef,
    float*       __restrict__ out)
{
    const int b = blockIdx.x;              // 2048 blocks: a*32 + c*4 + seg
    const int a = b >> 5;
    const int c = (b >> 2) & 7;
    const int n = ((b & 3) << 8) | threadIdx.x;
    const int warm = (c >= 2) ? 128 : 64 * c;   // c=0,1 exact; c>=2 approx
    const int t0   = 64 * c - warm;
    const int len  = warm + 64;

    __shared__ __align__(16) int   task_sh[216];
    __shared__ __align__(16) float coef_sh[216];
    __shared__ __align__(16) float ring[16 * 257];   // 16.4 KB, [slot][tid]

    for (int i = threadIdx.x; i < len + 16; i += 256) {
        const int t = t0 + i;
        task_sh[i] = (t < LXLEN) ? lx[t] : 0;
        coef_sh[i] = (t < LXLEN) ? coef[a * LXLEN + t] : 0.f;
    }

    const float mem   = mem_g[a];
    const float negkd = -1.4426950408889634f / diff[n];
    float* outp = out + ((size_t)a * NTASKS + n) * TOUT;
    float r = 0.f;
    float* ringc = ring + threadIdx.x;     // this thread's column

    // absolute float index of output v is ≡ n + 1 + v (mod 16)  (513≡1,
    // 64c≡0, 1024≡0 mod 16) -> granule phase is chunk-independent.
    const int phi = (n + 1) & 15;
    const int hp  = 16 - phi;              // head length, 1..16

    __syncthreads();

    float rbuf[16];
    #pragma unroll
    for (int j = 0; j < 16; ++j) {
        const int tk = __builtin_amdgcn_readfirstlane(task_sh[j]);
        rbuf[j] = tm[(size_t)tk * NTASKS + n];
    }

    // warmup: r-recurrence only, rolling 16-row pipeline
    for (int base = 0; base < warm; base += 16) {
        float nbuf[16];
        #pragma unroll
        for (int j = 0; j < 16; ++j) {
            const int tk = __builtin_amdgcn_readfirstlane(task_sh[base + 16 + j]);
            nbuf[j] = tm[(size_t)tk * NTASKS + n];
        }
        #pragma unroll
        for (int v = 0; v < 4; ++v) {
            const float4 cq = *(const float4*)&coef_sh[base + 4 * v];
            r = __builtin_fmaf(r, mem, rbuf[4 * v + 0] * cq.x);
            r = __builtin_fmaf(r, mem, rbuf[4 * v + 1] * cq.y);
            r = __builtin_fmaf(r, mem, rbuf[4 * v + 2] * cq.z);
            r = __builtin_fmaf(r, mem, rbuf[4 * v + 3] * cq.w);
        }
        #pragma unroll
        for (int j = 0; j < 16; ++j) rbuf[j] = nbuf[j];
    }

    if (c == 0) outp[0] = 0.f;
    float* op = outp + 64 * c + 1;

    #pragma unroll
    for (int kk = 0; kk < 4; ++kk) {       // 4 output rounds of 16
        const int base = warm + 16 * kk;
        float nbuf[16];
        #pragma unroll
        for (int j = 0; j < 16; ++j) {
            const int tk = __builtin_amdgcn_readfirstlane(task_sh[base + 16 + j]);
            nbuf[j] = tm[(size_t)tk * NTASKS + n];
        }
        float sb[16];
        #pragma unroll
        for (int v = 0; v < 4; ++v) {
            const float4 cq = *(const float4*)&coef_sh[base + 4 * v];
            const float cf[4] = { cq.x, cq.y, cq.z, cq.w };
            #pragma unroll
            for (int u = 0; u < 4; ++u) {
                const int j = 4 * v + u;
                r = __builtin_fmaf(r, mem, rbuf[j] * cf[u]);
                float x = r * negkd;
                x = fminf(fmaxf(x, -126.f), 126.f);
                const float e = __builtin_exp2f(x);
                sb[j] = (1.f - e) * __builtin_amdgcn_rcpf(1.f + e);
            }
        }

        if (kk == 0) {
            // head partial: v in [0,hp) straight from regs (predicated)
            #pragma unroll
            for (int j = 0; j < 16; ++j)
                if (j < hp) op[j] = sb[j];
            // stash v in [hp,16) -> slots [0,phi)
            #pragma unroll
            for (int j = 0; j < 16; ++j)
                if (j >= hp) ringc[(j - hp) * 257] = sb[j];
        } else {
            // 1. new head of granule kk-1 -> slots [phi,16)
            #pragma unroll
            for (int j = 0; j < 16; ++j)
                if (j < hp) ringc[(j + phi) * 257] = sb[j];
            // 2. flush granule kk-1 (slot i holds its i-th value), aligned
            float* dst = op + hp + 16 * (kk - 1);
            #pragma unroll
            for (int qd = 0; qd < 4; ++qd) {
                float4 w;
                w.x = ringc[(4 * qd + 0) * 257];
                w.y = ringc[(4 * qd + 1) * 257];
                w.z = ringc[(4 * qd + 2) * 257];
                w.w = ringc[(4 * qd + 3) * 257];
                ((float4*)dst)[qd] = w;
            }
            // 3. stash v in [16kk+hp,16kk+16) -> slots [0,phi)
            #pragma unroll
            for (int j = 0; j < 16; ++j)
                if (j >= hp) ringc[(j - hp) * 257] = sb[j];
        }
        #pragma unroll
        for (int j = 0; j < 16; ++j) rbuf[j] = nbuf[j];
    }

    // tail partial: v in [hp+48,64) sits in slots [0,phi) (predicated)
    #pragma unroll
    for (int j = 0; j < 16; ++j)
        if (j < phi) op[hp + 48 + j] = ringc[j * 257];
}

// ---------------------------------------------------------------------------
// Fallback (validated R1 kernel): used only if ws can't hold coef + P.
// ---------------------------------------------------------------------------
__global__ __launch_bounds__(1024) void fused_fallback_kernel(
    const int* __restrict__ lx, const float* __restrict__ tm,
    const float* __restrict__ diff, const float* __restrict__ eff_g,
    const float* __restrict__ mem_g, const float* __restrict__ boost_g,
    float* __restrict__ out)
{
    const int a = blockIdx.x, n = threadIdx.x;
    __shared__ int lx_sh[LXLEN];
    __shared__ float sbuf[2];
    if (n < LXLEN) lx_sh[n] = lx[n];
    if (n == 0) sbuf[0] = 0.0f;
    const float eff = eff_g[a], mem = mem_g[a], boost = boost_g[a];
    const float negkd = -1.4426950408889634f / diff[n];
    float* outp = out + ((size_t)a * NTASKS + n) * TOUT;
    outp[0] = 0.0f;
    float r = 0.0f;
    __syncthreads();
    for (int t = 0; t < LXLEN; ++t) {
        const int task = lx_sh[t];
        const float s = sbuf[t & 1];
        const float coef = __builtin_fmaf(s, boost, eff);
        const float row = tm[task * NTASKS + n];
        r = __builtin_fmaf(r, mem, row * coef);
        float x = r * negkd;
        x = fminf(fmaxf(x, -126.0f), 126.0f);
        const float e = __builtin_exp2f(x);
        const float sig = (1.0f - e) * __builtin_amdgcn_rcpf(1.0f + e);
        outp[t + 1] = sig;
        if (t + 1 < LXLEN && n == lx_sh[t + 1]) sbuf[(t + 1) & 1] = sig;
        __syncthreads();
    }
}

extern "C" void kernel_launch(void* const* d_in, const int* in_sizes, int n_in,
                              void* d_out, int out_size, void* d_ws, size_t ws_size,
                              hipStream_t stream) {
    const int*   lx    = (const int*)  d_in[0];
    const float* tm    = (const float*)d_in[1];
    const float* diff  = (const float*)d_in[2];
    const float* eff   = (const float*)d_in[3];
    const float* mem   = (const float*)d_in[4];
    const float* boost = (const float*)d_in[5];
    float* out = (float*)d_out;

    const size_t coef_elems = (size_t)NALGOS * LXLEN;
    const size_t P_elems    = (size_t)PROWS * LXLEN;
    const size_t need_bytes = (coef_elems + P_elems) * sizeof(float);

    if (ws_size >= need_bytes) {
        float* coef = (float*)d_ws;
        float* P    = coef + coef_elems;
        phase0_kernel<<<dim3(PROWS), dim3(256), 0, stream>>>(lx, tm, P);
        phase1_kernel<<<dim3(NALGOS), dim3(64), 0, stream>>>(
            lx, P, diff, eff, mem, boost, coef);
        phase2_kernel<<<dim3(NALGOS * 32), dim3(256), 0, stream>>>(
            lx, tm, diff, mem, coef, out);
    } else {
        fused_fallback_kernel<<<dim3(NALGOS), dim3(NTASKS), 0, stream>>>(
            lx, tm, diff, eff, mem, boost, out);
    }
}

// Round 4
// 225.858 us; speedup vs baseline: 2.6713x; 2.6687x over previous
//
#include <hip/hip_runtime.h>

#define NALGOS 64
#define NTASKS 1024
#define LXLEN  512
#define TOUT   (LXLEN + 1)   // 513
#define PROWS  (LXLEN + 8)   // 8 pad rows for phase1's t+8 prefetch overrun

__device__ __forceinline__ float rdlane(float v, int lane) {
    return __int_as_float(__builtin_amdgcn_readlane(__float_as_int(v), lane));
}

// ---------------------------------------------------------------------------
// Phase 0: materialize P[t][i] = tm[lx[t]][lx[i]] (512x512, 1 MB) with full
// parallelism so phase1's per-step loads become lane-coalesced.
// ---------------------------------------------------------------------------
__global__ __launch_bounds__(256) void phase0_kernel(
    const int* __restrict__ lx, const float* __restrict__ tm,
    float* __restrict__ P)
{
    const int t = blockIdx.x;          // 0..PROWS-1
    const int i = threadIdx.x;
    if (t < LXLEN) {
        const int row = lx[t] * NTASKS;
        P[t * LXLEN + i]       = tm[row + lx[i]];
        P[t * LXLEN + i + 256] = tm[row + lx[i + 256]];
    } else {                            // pad rows: loaded by phase1, unused
        P[t * LXLEN + i]       = 0.f;
        P[t * LXLEN + i + 256] = 0.f;
    }
}

// ---------------------------------------------------------------------------
// Phase 1: per-algo scalar coefficient chain. One wave per algo, 64 blocks.
// REVERTED to the round-0/1 PDEPTH=8 version (measured ~39 us). The PDEPTH=16
// variant spilled G to scratch (VGPR capped at 92 both with and without
// launch_bounds(64,1) -> 402 us). Lane l, reg q holds V[i]=result[lx[i]] for
// i=q*64+l; chain scalar via v_readlane; refill lane-coalesced from P.
// ---------------------------------------------------------------------------
__global__ __launch_bounds__(64) void phase1_kernel(
    const int*   __restrict__ lx,
    const float* __restrict__ P,
    const float* __restrict__ diff,
    const float* __restrict__ eff_g,
    const float* __restrict__ mem_g,
    const float* __restrict__ boost_g,
    float*       __restrict__ coef_out)
{
    const int a = blockIdx.x, lane = threadIdx.x;

    float nk[8]; float V[8];
    #pragma unroll
    for (int k = 0; k < 8; ++k) {
        const int tsk = lx[lane + 64 * k];
        nk[k] = -1.4426950408889634f / diff[tsk];
        V[k] = 0.f;
    }
    const float eff = eff_g[a], mem = mem_g[a], boost = boost_g[a];

    // prime 8-deep row pipeline: G[d][k] = P[d][64k+lane], d = 0..7
    float G[8][8];
    #pragma unroll
    for (int d = 0; d < 8; ++d)
        #pragma unroll
        for (int k = 0; k < 8; ++k)
            G[d][k] = P[d * LXLEN + 64 * k + lane];

    float coef = eff;
    float* cout = coef_out + (size_t)a * LXLEN;

    #pragma unroll
    for (int q = 0; q < 8; ++q) {
        float cbuf = 0.f;
        for (int g = 0; g < 8; ++g) {
            const int tb = q * 64 + g * 8;
            #pragma unroll
            for (int j = 0; j < 8; ++j) {
                // ---- serial chain ----
                const float p = V[q] * nk[q];
                float x = rdlane(p, g * 8 + j);       // V_{t-1}[t]*nk_t, uniform
                x = fminf(fmaxf(x, -126.f), 126.f);
                const float e = __builtin_exp2f(x);
                const float u = (1.f - e) * __builtin_amdgcn_rcpf(1.f + e);
                coef = __builtin_fmaf(u, boost, eff);
                cbuf = (lane == g * 8 + j) ? coef : cbuf;
                // ---- V update, future regs only ----
                #pragma unroll
                for (int k = q; k < 8; ++k)
                    V[k] = __builtin_fmaf(V[k], mem, G[j][k] * coef);
                // ---- refill row t+8, lane-coalesced ----
                const float* rp = P + (tb + j + 8) * LXLEN + lane;
                #pragma unroll
                for (int k = q; k < 8; ++k)
                    G[j][k] = rp[64 * k];
            }
        }
        cout[q * 64 + lane] = cbuf;                   // coalesced, 1/chunk
    }
}

// ---------------------------------------------------------------------------
// Phase 2: write-TRANSACTION-bound fix. Evidence: fill=538MB/84us (6.4TB/s,
// 64B txns) and old phase2=150MB/73us (2TB/s, 16B txns) run at the SAME
// ~100-130 Gtxn/s; extra waves (r2) changed nothing. Old txns/row ~224
// (scattered 16B dwordx4 flushes + 16 scalar partials x 8 chunk-splits).
// New: (1) per-row alignment d(n)=(-n)&15 -- out-index == n+t (mod 16), so
// each block emits the aligned 64-value window [64c+d, 64c+d+64) per row;
// uniform 80-step rounds + 32-slot LDS ring absorb the skew; partials exist
// only at true row head (c=0) / tail (c=7). (2) quad-cooperative flush:
// 16-lane groups store one CONTIGUOUS 64B-aligned granule of a sibling
// thread (ds_read transposed ring + store_dword) -> 4x64B txns per instr
// instead of 64x16B. Net ~47 txns/row (~4.8x fewer). The t=-1 dummy step
// (task=0, coef=0, r=0 -> sig=0) makes the u=0 zero-column fall out of the
// uniform loop. Warmup: c=0,1 exact; c>=2 start 129 before first output
// step (mem^128 ~ 1e-12, same approximation as before).
// LDS 36.5KB -> 4 blocks/CU (16 waves); launch_bounds(256,4) -> <=128 VGPR.
// ---------------------------------------------------------------------------
__global__ __launch_bounds__(256, 4) void phase2_kernel(
    const int*   __restrict__ lx,
    const float* __restrict__ tm,
    const float* __restrict__ diff,
    const float* __restrict__ mem_g,
    const float* __restrict__ coef,
    float*       __restrict__ out)
{
    const int b   = blockIdx.x;            // 2048 blocks: a*32 + c*4 + seg
    const int a   = b >> 5;
    const int c   = (b >> 2) & 7;
    const int seg = b & 3;
    const int tid = threadIdx.x;
    const int n   = (seg << 8) | tid;

    const int warm = (c >= 2) ? 128 : 64 * c;   // c=0,1 exact; c>=2 approx
    const int t0   = 64 * c - 1 - warm;         // t for array index 0 (may be -1)

    __shared__ __align__(16) int   task_sh[224];
    __shared__ __align__(16) float coef_sh[224];
    __shared__ __align__(16) float ring[32 * 257];   // 32.9 KB, [slot][tid]

    const int nfill = warm + 96;
    for (int i = tid; i < nfill; i += 256) {
        const int t = t0 + i;
        const bool ok = (t >= 0) && (t < LXLEN);
        task_sh[i] = ok ? lx[t] : 0;
        coef_sh[i] = ok ? coef[a * LXLEN + t] : 0.f;
    }

    const float mem   = mem_g[a];
    const float negkd = -1.4426950408889634f / diff[n];
    const int   d     = (16 - (n & 15)) & 15;   // granule phase of row n
    float* rowp = out + ((size_t)a * NTASKS + n) * TOUT;
    float  r    = 0.f;
    float* ringc = ring + tid;                  // this thread's column

    // cooperative-flush lane roles (within own wave only -> no barriers)
    const int wb = tid & 192;                   // wave base thread
    const int lq = tid & 15;                    // float within granule
    const int qq = (tid >> 4) & 3;              // quad id 0..3

    __syncthreads();

    float rbuf[16];
    #pragma unroll
    for (int j = 0; j < 16; ++j) {
        const int tk = __builtin_amdgcn_readfirstlane(task_sh[j]);
        rbuf[j] = tm[(size_t)tk * NTASKS + n];
    }

    // warmup: r-recurrence only, rolling 16-row pipeline (warm = 0/64/128)
    for (int base = 0; base < warm; base += 16) {
        float nbuf[16];
        #pragma unroll
        for (int j = 0; j < 16; ++j) {
            const int tk = __builtin_amdgcn_readfirstlane(task_sh[base + 16 + j]);
            nbuf[j] = tm[(size_t)tk * NTASKS + n];
        }
        #pragma unroll
        for (int v = 0; v < 4; ++v) {
            const float4 cq = *(const float4*)&coef_sh[base + 4 * v];
            r = __builtin_fmaf(r, mem, rbuf[4 * v + 0] * cq.x);
            r = __builtin_fmaf(r, mem, rbuf[4 * v + 1] * cq.y);
            r = __builtin_fmaf(r, mem, rbuf[4 * v + 2] * cq.z);
            r = __builtin_fmaf(r, mem, rbuf[4 * v + 3] * cq.w);
        }
        #pragma unroll
        for (int j = 0; j < 16; ++j) rbuf[j] = nbuf[j];
    }

    // output: 5 rounds of 16 uniform steps; step index s = 16*rr + j,
    // out position u = 64c + s, recurrence step t = u - 1 (t=-1 is the
    // padded dummy -> sig = 0 lands exactly at the u=0 zero column).
    #pragma unroll
    for (int rr = 0; rr < 5; ++rr) {
        const int base = warm + 16 * rr;
        float nbuf[16];
        #pragma unroll
        for (int j = 0; j < 16; ++j) {
            const int tk = __builtin_amdgcn_readfirstlane(task_sh[base + 16 + j]);
            nbuf[j] = tm[(size_t)tk * NTASKS + n];
        }
        #pragma unroll
        for (int v = 0; v < 4; ++v) {
            const float4 cq = *(const float4*)&coef_sh[base + 4 * v];
            const float cf[4] = { cq.x, cq.y, cq.z, cq.w };
            #pragma unroll
            for (int u4 = 0; u4 < 4; ++u4) {
                const int j = 4 * v + u4;
                r = __builtin_fmaf(r, mem, rbuf[j] * cf[u4]);
                float x = r * negkd;
                x = fminf(fmaxf(x, -126.f), 126.f);
                const float e = __builtin_exp2f(x);
                const float sig = (1.f - e) * __builtin_amdgcn_rcpf(1.f + e);
                // ring slot (s - d) & 31
                ringc[((16 * rr + j - d) & 31) * 257] = sig;
                // c=0 ragged row-head: u in [0, d) straight from regs
                if (c == 0 && rr == 0 && j < d) rowp[j] = sig;
            }
        }
        // cooperative flush of granule g = rr-1 for this wave's 64 threads:
        // 16-lane groups each store one contiguous 64B-aligned granule.
        if (rr >= 1) {
            const int g    = rr - 1;
            const int sb16 = (g & 1) << 4;      // ring slot base (mod 32)
            #pragma unroll
            for (int sub = 0; sub < 16; ++sub) {
                const int tau = wb + 4 * sub + qq;       // target thread
                const int nn  = (seg << 8) | tau;        // its row
                const int dd  = (16 - qq - 4 * (sub & 3)) & 15;  // = d(nn)
                const float vv = ring[(sb16 + lq) * 257 + tau];
                // c=7 granule 3 exists only for dd<=1 (else exceeds u=512)
                if (!(c == 7 && g == 3 && dd > 1)) {
                    out[((size_t)a * NTASKS + nn) * TOUT
                        + 64 * c + dd + 16 * g + lq] = vv;
                }
            }
        }
        #pragma unroll
        for (int j = 0; j < 16; ++j) rbuf[j] = nbuf[j];
    }

    // c=7 ragged row-tail from own ring column:
    //   d==1: nothing (granule 3 ended exactly at u=512)
    //   d==0: u=512 only; d>=2: u in [496+d, 512]
    if (c == 7) {
        const int tt0 = (d == 1) ? 513 : ((d == 0) ? 512 : 496 + d);
        #pragma unroll
        for (int u = 496; u <= 512; ++u) {
            if (u >= tt0) rowp[u] = ringc[(((u - 448) - d) & 31) * 257];
        }
    }
}

// ---------------------------------------------------------------------------
// Fallback (validated R1 kernel): used only if ws can't hold coef + P.
// ---------------------------------------------------------------------------
__global__ __launch_bounds__(1024) void fused_fallback_kernel(
    const int* __restrict__ lx, const float* __restrict__ tm,
    const float* __restrict__ diff, const float* __restrict__ eff_g,
    const float* __restrict__ mem_g, const float* __restrict__ boost_g,
    float* __restrict__ out)
{
    const int a = blockIdx.x, n = threadIdx.x;
    __shared__ int lx_sh[LXLEN];
    __shared__ float sbuf[2];
    if (n < LXLEN) lx_sh[n] = lx[n];
    if (n == 0) sbuf[0] = 0.0f;
    const float eff = eff_g[a], mem = mem_g[a], boost = boost_g[a];
    const float negkd = -1.4426950408889634f / diff[n];
    float* outp = out + ((size_t)a * NTASKS + n) * TOUT;
    outp[0] = 0.0f;
    float r = 0.0f;
    __syncthreads();
    for (int t = 0; t < LXLEN; ++t) {
        const int task = lx_sh[t];
        const float s = sbuf[t & 1];
        const float coef = __builtin_fmaf(s, boost, eff);
        const float row = tm[task * NTASKS + n];
        r = __builtin_fmaf(r, mem, row * coef);
        float x = r * negkd;
        x = fminf(fmaxf(x, -126.0f), 126.0f);
        const float e = __builtin_exp2f(x);
        const float sig = (1.0f - e) * __builtin_amdgcn_rcpf(1.0f + e);
        outp[t + 1] = sig;
        if (t + 1 < LXLEN && n == lx_sh[t + 1]) sbuf[(t + 1) & 1] = sig;
        __syncthreads();
    }
}

extern "C" void kernel_launch(void* const* d_in, const int* in_sizes, int n_in,
                              void* d_out, int out_size, void* d_ws, size_t ws_size,
                              hipStream_t stream) {
    const int*   lx    = (const int*)  d_in[0];
    const float* tm    = (const float*)d_in[1];
    const float* diff  = (const float*)d_in[2];
    const float* eff   = (const float*)d_in[3];
    const float* mem   = (const float*)d_in[4];
    const float* boost = (const float*)d_in[5];
    float* out = (float*)d_out;

    const size_t coef_elems = (size_t)NALGOS * LXLEN;
    const size_t P_elems    = (size_t)PROWS * LXLEN;
    const size_t need_bytes = (coef_elems + P_elems) * sizeof(float);

    if (ws_size >= need_bytes) {
        float* coef = (float*)d_ws;
        float* P    = coef + coef_elems;
        phase0_kernel<<<dim3(PROWS), dim3(256), 0, stream>>>(lx, tm, P);
        phase1_kernel<<<dim3(NALGOS), dim3(64), 0, stream>>>(
            lx, P, diff, eff, mem, boost, coef);
        phase2_kernel<<<dim3(NALGOS * 32), dim3(256), 0, stream>>>(
            lx, tm, diff, mem, coef, out);
    } else {
        fused_fallback_kernel<<<dim3(NALGOS), dim3(NTASKS), 0, stream>>>(
            lx, tm, diff, eff, mem, boost, out);
    }
}